// Round 9
// baseline (154.502 us; speedup 1.0000x reference)
//
#include <hip/hip_runtime.h>

// out[b,h] = sum_{i,j} cb[h, i*64+j] * in1[b,i] * in2[b,j]
// B = 4096, dim1 = dim2 = 64, H = 4096.
//
// Round-8 = round-7 compute core (float2 batch packing, pair fusion, VGPR
// cb prefetch, readlane broadcast) with the stall structure removed:
//   - NO so tile, NO flush, ONE barrier total: each lane writes its pair
//     rows directly as float2 {h=2w, 2w+1} per batch. The 16 h-dwords of
//     each 64B out segment come from the 8 waves of the same block in the
//     same quarter -> L2 merges into full lines.
//   - heavy-first dispatch: h0 = (63 - blockIdx.y)*64. Work per h-tile
//     varies ~50x (l3=0 rows are 1 MAC, l3=6 rows are 49); linear order
//     would run heavy tiles last -> tail. Flip it.

typedef float vf2 __attribute__((ext_vector_type(2)));

#define SDIM 65   // s1v/s2v row stride in float2 units

__constant__ int   kStart[7] = {0, 64, 496, 1376, 2496, 3360, 3888};
__constant__ unsigned kMagic[7] = {262144u, 87382u, 52429u, 37450u, 29128u, 23832u, 20165u}; // 2^18/d rounded up, d=2*l3+1
__constant__ int   kVpOff[7] = {0, 4, 13, 24, 34, 40, 43};
__constant__ unsigned char kVp[44] = {
  0, 5, 10, 15,                                  // l3=0
  1, 4, 5, 6, 9, 10, 11, 14, 15,                 // l3=1
  2, 5, 6, 7, 8, 9, 10, 11, 13, 14, 15,          // l3=2 ((1,3) before (2,0))
  3, 6, 7, 9, 10, 11, 12, 13, 14, 15,            // l3=3 ((2,3) before (3,0))
  7, 10, 11, 13, 14, 15,                         // l3=4
  11, 14, 15,                                    // l3=5
  15};                                           // l3=6
__constant__ int kBase[4] = {0, 4, 16, 36};  // offset of first slot of each l

__device__ __forceinline__ void decode_h(int h, int& i1, int& i2,
                                         int& n1, int& n2, int& l1l2) {
  int l3 = (h >= 64) + (h >= 496) + (h >= 1376) + (h >= 2496) + (h >= 3360) + (h >= 3888);
  unsigned hl = (unsigned)(h - kStart[l3]);
  int pair = (int)((hl * kMagic[l3]) >> 18);   // hl / (2*l3+1), exact in range
  int slot = pair & 15;
  int vp   = pair >> 4;
  l1l2 = (int)kVp[kVpOff[l3] + vp];
  int l1 = l1l2 >> 2, l2 = l1l2 & 3;
  n1 = 2 * l1 + 1;
  n2 = 2 * l2 + 1;
  i1 = kBase[l1] + (slot >> 2) * n1;
  i2 = kBase[l2] + (slot & 3) * n2;
}

// ---- prep: compact cb rows + decode metadata ----
__global__ __launch_bounds__(256) void prep_kernel(const float* __restrict__ cb,
                                                   float* __restrict__ table,
                                                   int* __restrict__ meta) {
  int idx = blockIdx.x * 256 + threadIdx.x;   // 1024 blocks -> 262144 = 4096*64
  int h = idx >> 6, e = idx & 63;
  int i1, i2, n1, n2, c;
  decode_h(h, i1, i2, n1, n2, c);
  if (e == 0) meta[h] = i1 | (i2 << 8) | (c << 16);
  unsigned mg = (n2 == 1) ? 65536u : (n2 == 3) ? 21846u : (n2 == 5) ? 13108u : 9363u;
  int qi = (int)(((unsigned)e * mg) >> 16);   // e / n2, exact for e < 64
  int rj = e - qi * n2;
  float v = 0.f;
  if (e < n1 * n2) v = cb[(size_t)h * 4096 + (i1 + qi) * 64 + (i2 + rj)];
  table[(size_t)h * 64 + e] = v;
}

__device__ __forceinline__ float lane_bcast(float v, int l) {
  union { float f; int i; } u;
  u.f = v;
  u.i = __builtin_amdgcn_readlane(u.i, l);
  return u.f;
}

__device__ __forceinline__ vf2 splat(float c) { vf2 r; r.x = c; r.y = c; return r; }

// single row, 2 batches packed
template <int N1, int N2>
__device__ __forceinline__ vf2 inner_tp(float vrow,
                                        const vf2* __restrict__ s1r,
                                        const vf2* __restrict__ s2r,
                                        int i1, int i2) {
  vf2 bb[N2], aa[N1];
#pragma unroll
  for (int j = 0; j < N2; ++j) bb[j] = s2r[i2 + j];   // ds_read2_b64
#pragma unroll
  for (int i = 0; i < N1; ++i) aa[i] = s1r[i1 + i];
  vf2 acc0 = splat(0.f), acc1 = splat(0.f);
#pragma unroll
  for (int i = 0; i < N1; ++i) {
    vf2 t = splat(lane_bcast(vrow, i * N2)) * bb[0];
#pragma unroll
    for (int j = 1; j < N2; ++j)
      t = __builtin_elementwise_fma(splat(lane_bcast(vrow, i * N2 + j)), bb[j], t);
    if (i & 1) acc1 = __builtin_elementwise_fma(aa[i], t, acc1);
    else       acc0 = __builtin_elementwise_fma(aa[i], t, acc0);
  }
  return acc0 + acc1;
}

// fused same-run pair x 2 batches: aa/bb loaded once for both rows
template <int N1, int N2>
__device__ __forceinline__ void inner_tp2(float v0, float v1,
                                          const vf2* __restrict__ s1r,
                                          const vf2* __restrict__ s2r,
                                          int i1, int i2,
                                          vf2& o0, vf2& o1) {
  vf2 bb[N2], aa[N1];
#pragma unroll
  for (int j = 0; j < N2; ++j) bb[j] = s2r[i2 + j];
#pragma unroll
  for (int i = 0; i < N1; ++i) aa[i] = s1r[i1 + i];
  vf2 a0 = splat(0.f), a1 = splat(0.f), b0 = splat(0.f), b1 = splat(0.f);
#pragma unroll
  for (int i = 0; i < N1; ++i) {
    vf2 t0 = splat(lane_bcast(v0, i * N2)) * bb[0];
    vf2 t1 = splat(lane_bcast(v1, i * N2)) * bb[0];
#pragma unroll
    for (int j = 1; j < N2; ++j) {
      t0 = __builtin_elementwise_fma(splat(lane_bcast(v0, i * N2 + j)), bb[j], t0);
      t1 = __builtin_elementwise_fma(splat(lane_bcast(v1, i * N2 + j)), bb[j], t1);
    }
    if (i & 1) { a1 = __builtin_elementwise_fma(aa[i], t0, a1);
                 b1 = __builtin_elementwise_fma(aa[i], t1, b1); }
    else       { a0 = __builtin_elementwise_fma(aa[i], t0, a0);
                 b0 = __builtin_elementwise_fma(aa[i], t1, b0); }
  }
  o0 = a0 + a1;
  o1 = b0 + b1;
}

__global__ __launch_bounds__(512) void tp_kernel(
    const float* __restrict__ in1, const float* __restrict__ in2,
    const float* __restrict__ table, const int* __restrict__ meta,
    float* __restrict__ out) {
  __shared__ vf2 s1v[64 * SDIM];    // [batch_pair][dim], float2 = (b2t, b2t+1)
  __shared__ vf2 s2v[64 * SDIM];

  const int tid = threadIdx.x;
  const int b0 = blockIdx.x << 7;           // batch tile (128)
  const int h0 = (63 - blockIdx.y) << 6;    // h tile (64), heavy-first
  const int w = tid >> 6;                   // wave id 0..7: rows (16q+2w, +1)
  const int t = tid & 63;                   // lane = batch PAIR (2t, 2t+1)

  // wave's cb-table rows; lane t holds entry t. Prefetch quarter 0 now.
  const float* tb = table + ((size_t)(h0 + 2 * w) << 6) + t;
  float cur0 = tb[0];
  float cur1 = tb[64];
  const int2* meta2 = reinterpret_cast<const int2*>(meta);
  int2 mcur = meta2[__builtin_amdgcn_readfirstlane((h0 >> 1) + w)];

  // ---- stage in1/in2 tiles, interleaving batch pairs into float2 ----
#pragma unroll
  for (int it = 0; it < 2; ++it) {
    int task = it * 512 + tid;         // 1024 tasks = 64 pairs x 16 float4
    int bp = task >> 4;                // batch pair 0..63
    int d4 = (task & 15) << 2;         // dim start
    const float* r0p = in1 + (size_t)(b0 + 2 * bp) * 64 + d4;
    const float* r1p = r0p + 64;
    float4 a0 = *reinterpret_cast<const float4*>(r0p);
    float4 a1 = *reinterpret_cast<const float4*>(r1p);
    vf2* p = &s1v[bp * SDIM + d4];
    vf2 u;
    u.x = a0.x; u.y = a1.x; p[0] = u;
    u.x = a0.y; u.y = a1.y; p[1] = u;
    u.x = a0.z; u.y = a1.z; p[2] = u;
    u.x = a0.w; u.y = a1.w; p[3] = u;
    const float* q0p = in2 + (size_t)(b0 + 2 * bp) * 64 + d4;
    const float* q1p = q0p + 64;
    float4 c0 = *reinterpret_cast<const float4*>(q0p);
    float4 c1 = *reinterpret_cast<const float4*>(q1p);
    vf2* p2 = &s2v[bp * SDIM + d4];
    u.x = c0.x; u.y = c1.x; p2[0] = u;
    u.x = c0.y; u.y = c1.y; p2[1] = u;
    u.x = c0.z; u.y = c1.z; p2[2] = u;
    u.x = c0.w; u.y = c1.w; p2[3] = u;
  }
  __syncthreads();   // the only barrier in the kernel

  const vf2* s1r = &s1v[t * SDIM];
  const vf2* s2r = &s2v[t * SDIM];

#pragma unroll 1
  for (int q = 0; q < 4; ++q) {
    // prefetch next quarter's cb pair + meta (clamped on last iteration)
    int qn = (q < 3) ? (q + 1) : 0;
    float nxt0 = tb[qn << 10];
    float nxt1 = tb[(qn << 10) + 64];
    int2 mnxt = meta2[__builtin_amdgcn_readfirstlane((h0 >> 1) + 8 * qn + w)];

    int mm0 = mcur.x, mm1 = mcur.y;
    vf2 r0 = splat(0.f), r1 = splat(0.f);
    if (mm0 == mm1) {
      int i1 = mm0 & 255, i2 = (mm0 >> 8) & 255;
#define TP2_CASE(L1, L2) \
      case (L1 * 4 + L2): inner_tp2<2 * L1 + 1, 2 * L2 + 1>(cur0, cur1, s1r, s2r, i1, i2, r0, r1); break;
      switch (mm0 >> 16) {
        TP2_CASE(0, 0) TP2_CASE(0, 1) TP2_CASE(0, 2) TP2_CASE(0, 3)
        TP2_CASE(1, 0) TP2_CASE(1, 1) TP2_CASE(1, 2) TP2_CASE(1, 3)
        TP2_CASE(2, 0) TP2_CASE(2, 1) TP2_CASE(2, 2) TP2_CASE(2, 3)
        TP2_CASE(3, 0) TP2_CASE(3, 1) TP2_CASE(3, 2) TP2_CASE(3, 3)
        default: break;
      }
#undef TP2_CASE
    } else {
#define TP_CASE(L1, L2, VR, DST, MI1, MI2) \
      case (L1 * 4 + L2): DST = inner_tp<2 * L1 + 1, 2 * L2 + 1>(VR, s1r, s2r, MI1, MI2); break;
      {
        int i1 = mm0 & 255, i2 = (mm0 >> 8) & 255;
        switch (mm0 >> 16) {
          TP_CASE(0, 0, cur0, r0, i1, i2) TP_CASE(0, 1, cur0, r0, i1, i2)
          TP_CASE(0, 2, cur0, r0, i1, i2) TP_CASE(0, 3, cur0, r0, i1, i2)
          TP_CASE(1, 0, cur0, r0, i1, i2) TP_CASE(1, 1, cur0, r0, i1, i2)
          TP_CASE(1, 2, cur0, r0, i1, i2) TP_CASE(1, 3, cur0, r0, i1, i2)
          TP_CASE(2, 0, cur0, r0, i1, i2) TP_CASE(2, 1, cur0, r0, i1, i2)
          TP_CASE(2, 2, cur0, r0, i1, i2) TP_CASE(2, 3, cur0, r0, i1, i2)
          TP_CASE(3, 0, cur0, r0, i1, i2) TP_CASE(3, 1, cur0, r0, i1, i2)
          TP_CASE(3, 2, cur0, r0, i1, i2) TP_CASE(3, 3, cur0, r0, i1, i2)
          default: break;
        }
      }
      {
        int i1 = mm1 & 255, i2 = (mm1 >> 8) & 255;
        switch (mm1 >> 16) {
          TP_CASE(0, 0, cur1, r1, i1, i2) TP_CASE(0, 1, cur1, r1, i1, i2)
          TP_CASE(0, 2, cur1, r1, i1, i2) TP_CASE(0, 3, cur1, r1, i1, i2)
          TP_CASE(1, 0, cur1, r1, i1, i2) TP_CASE(1, 1, cur1, r1, i1, i2)
          TP_CASE(1, 2, cur1, r1, i1, i2) TP_CASE(1, 3, cur1, r1, i1, i2)
          TP_CASE(2, 0, cur1, r1, i1, i2) TP_CASE(2, 1, cur1, r1, i1, i2)
          TP_CASE(2, 2, cur1, r1, i1, i2) TP_CASE(2, 3, cur1, r1, i1, i2)
          TP_CASE(3, 0, cur1, r1, i1, i2) TP_CASE(3, 1, cur1, r1, i1, i2)
          TP_CASE(3, 2, cur1, r1, i1, i2) TP_CASE(3, 3, cur1, r1, i1, i2)
          default: break;
        }
      }
#undef TP_CASE
    }
    // ---- direct store: rows (2w, 2w+1) adjacent in h -> float2 per batch.
    // 8 waves of this block fill all 16 dwords of each 64B segment in this
    // quarter -> L2 merges to full lines.
    {
      int hbase = h0 + 16 * q + 2 * w;
      float2 va; va.x = r0.x; va.y = r1.x;   // batch 2t
      float2 vb; vb.x = r0.y; vb.y = r1.y;   // batch 2t+1
      float* o0 = out + (size_t)(b0 + 2 * t) * 4096 + hbase;
      *reinterpret_cast<float2*>(o0) = va;
      *reinterpret_cast<float2*>(o0 + 4096) = vb;
    }
    cur0 = nxt0; cur1 = nxt1;
    mcur = mnxt;
  }
}

extern "C" void kernel_launch(void* const* d_in, const int* in_sizes, int n_in,
                              void* d_out, int out_size, void* d_ws, size_t ws_size,
                              hipStream_t stream) {
  const float* in1 = (const float*)d_in[0];
  const float* in2 = (const float*)d_in[1];
  const float* cb  = (const float*)d_in[2];
  float* out = (float*)d_out;
  float* table = (float*)d_ws;                       // 4096*64*4 = 1 MB
  int* meta = (int*)((char*)d_ws + (size_t)4096 * 64 * 4);   // +16 KB
  (void)in_sizes; (void)n_in; (void)out_size; (void)ws_size;
  prep_kernel<<<1024, 256, 0, stream>>>(cb, table, meta);
  tp_kernel<<<dim3(32, 64), 512, 0, stream>>>(in1, in2, table, meta, out);
}